// Round 8
// baseline (119.028 us; speedup 1.0000x reference)
//
#include <hip/hip_runtime.h>
#include <hip/hip_bf16.h>

constexpr int N_NODES = 100000;
constexpr int DIM     = 128;
constexpr int N_EDGES = 640000;

constexpr int CHUNK     = 1024;
constexpr int N_CHUNKS  = (N_NODES + CHUNK - 1) / CHUNK;   // 98
constexpr int BINCAP    = 8192;
constexpr int EPB       = 1024;
constexpr int SRC_BITS  = 17;
constexpr int SRC_MASK  = (1 << SRC_BITS) - 1;

constexpr int XCONV_XBLOCKS = N_NODES * DIM / (256 * 8);   // 6250
constexpr int XCONV_WBLOCKS = DIM * DIM / (256 * 8);       // 8

constexpr int FUSE_NODES  = 64;                            // nodes per fused block
constexpr int FUSE_BLOCKS = (N_NODES + FUSE_NODES - 1) / FUSE_NODES;  // 1563
constexpr int HPAD        = DIM + 8;                       // 136 bf16 = 272 B rows

typedef __attribute__((ext_vector_type(4))) float        f32x4;
typedef __attribute__((ext_vector_type(8))) short        bf16x8;
typedef __attribute__((ext_vector_type(4))) unsigned int u32x4;

static __device__ inline unsigned short f2bf(float f) {
    __hip_bfloat16 h = __float2bfloat16(f);   // RNE
    return *reinterpret_cast<unsigned short*>(&h);
}
static __device__ inline float bf_lo(unsigned u) { return __uint_as_float(u << 16); }
static __device__ inline float bf_hi(unsigned u) { return __uint_as_float(u & 0xffff0000u); }

// ---------------------------------------------------------------------------
// 1) Fused: x->bf16 (-> ws), W->bf16, zero the 98 bin cursors.
// ---------------------------------------------------------------------------
__global__ __launch_bounds__(256) void gcn_conv(const float* __restrict__ x,
                                                const float* __restrict__ W,
                                                unsigned int* __restrict__ xb,
                                                unsigned int* __restrict__ wb,
                                                int* __restrict__ bincur)
{
    const int b   = blockIdx.x;
    const int gid = b * 256 + threadIdx.x;

    if (b == 0 && threadIdx.x < 128) bincur[threadIdx.x] = 0;

    const float*  src;
    unsigned int* dst;
    int i;
    if (b < XCONV_XBLOCKS) {
        src = x;  dst = xb;  i = gid;
    } else {
        src = W;  dst = wb;  i = gid - XCONV_XBLOCKS * 256;
    }
    const f32x4* s4 = reinterpret_cast<const f32x4*>(src);
    f32x4 a = s4[2 * i];
    f32x4 c = s4[2 * i + 1];
    u32x4 o;
    o.x = (unsigned)f2bf(a.x) | ((unsigned)f2bf(a.y) << 16);
    o.y = (unsigned)f2bf(a.z) | ((unsigned)f2bf(a.w) << 16);
    o.z = (unsigned)f2bf(c.x) | ((unsigned)f2bf(c.y) << 16);
    o.w = (unsigned)f2bf(c.z) | ((unsigned)f2bf(c.w) << 16);
    reinterpret_cast<u32x4*>(dst)[i] = o;
}

// ---------------------------------------------------------------------------
// 2) Bin pass: scatter edges into per-chunk regions (packed src|dstlocal).
// ---------------------------------------------------------------------------
__global__ __launch_bounds__(256) void gcn_bin(const int* __restrict__ src,
                                               const int* __restrict__ dst,
                                               int* __restrict__ bincur,
                                               unsigned int* __restrict__ bindata)
{
    __shared__ int bh[N_CHUNKS];
    __shared__ int btb[N_CHUNKS];

    const int t  = threadIdx.x;
    const int e0 = blockIdx.x * EPB + t * 4;

    if (t < N_CHUNKS) bh[t] = 0;
    __syncthreads();

    const int4 s4 = *reinterpret_cast<const int4*>(src + e0);
    const int4 d4 = *reinterpret_cast<const int4*>(dst + e0);

    int bin[4], pos[4];
    unsigned pv[4];
    const int ds[4] = {d4.x, d4.y, d4.z, d4.w};
    const int ss[4] = {s4.x, s4.y, s4.z, s4.w};
    #pragma unroll
    for (int q = 0; q < 4; ++q) {
        bin[q] = ds[q] >> 10;
        pv[q]  = (unsigned)ss[q] | ((unsigned)(ds[q] & (CHUNK - 1)) << SRC_BITS);
        pos[q] = atomicAdd(&bh[bin[q]], 1);
    }
    __syncthreads();

    if (t < N_CHUNKS) btb[t] = atomicAdd(&bincur[t], bh[t]);
    __syncthreads();

    #pragma unroll
    for (int q = 0; q < 4; ++q)
        bindata[(size_t)bin[q] * BINCAP + btb[bin[q]] + pos[q]] = pv[q];
}

// ---------------------------------------------------------------------------
// 3) Build pass: per-chunk LDS counting sort -> dense csr + off metadata.
// ---------------------------------------------------------------------------
__global__ __launch_bounds__(256) void gcn_build(const int* __restrict__ bincur,
                                                 unsigned int* __restrict__ bindata,
                                                 int* __restrict__ off)
{
    __shared__ unsigned stage[BINCAP];
    __shared__ int hist[CHUNK];
    __shared__ int s[256];

    const int c  = blockIdx.x;
    const int t  = threadIdx.x;
    const int nb = min(bincur[c], BINCAP);
    unsigned int* region = bindata + (size_t)c * BINCAP;

    for (int e = t; e < nb; e += 256) stage[e] = region[e];
    #pragma unroll
    for (int q = 0; q < 4; ++q) hist[t + 256 * q] = 0;
    __syncthreads();

    for (int e = t; e < nb; e += 256)
        atomicAdd(&hist[stage[e] >> SRC_BITS], 1);
    __syncthreads();

    int h0 = hist[4 * t + 0], h1 = hist[4 * t + 1];
    int h2 = hist[4 * t + 2], h3 = hist[4 * t + 3];
    s[t] = h0 + h1 + h2 + h3;
    __syncthreads();
    for (int d = 1; d < 256; d <<= 1) {
        int add = (t >= d) ? s[t - d] : 0;
        __syncthreads();
        s[t] += add;
        __syncthreads();
    }
    int excl = (t > 0) ? s[t - 1] : 0;

    const int st0 = excl;
    const int st1 = excl + h0;
    const int st2 = excl + h0 + h1;
    const int st3 = excl + h0 + h1 + h2;
    hist[4 * t + 0] = st0;  hist[4 * t + 1] = st1;
    hist[4 * t + 2] = st2;  hist[4 * t + 3] = st3;

    const int nbase = c * CHUNK;
    if (nbase + 4 * t + 0 < N_NODES) off[nbase + 4 * t + 0] = st0 | (h0 << 13);
    if (nbase + 4 * t + 1 < N_NODES) off[nbase + 4 * t + 1] = st1 | (h1 << 13);
    if (nbase + 4 * t + 2 < N_NODES) off[nbase + 4 * t + 2] = st2 | (h2 << 13);
    if (nbase + 4 * t + 3 < N_NODES) off[nbase + 4 * t + 3] = st3 | (h3 << 13);
    __syncthreads();

    for (int e = t; e < nb; e += 256) {
        unsigned v  = stage[e];
        int slot    = atomicAdd(&hist[v >> SRC_BITS], 1);
        region[slot] = v & SRC_MASK;
    }
}

// ---------------------------------------------------------------------------
// 4) FUSED gather + MFMA: per block, 64 nodes.
//    Phase A: 4 sweeps x (16 nodes, 16 lanes/node) -> h bf16 into LDS [64][136].
//    Phase B: 4 waves, wave w MFMAs rows [16w,16w+16), W streamed per c-column.
// ---------------------------------------------------------------------------
static __device__ inline void acc8(float* acc, u32x4 v) {
    #pragma unroll
    for (int q = 0; q < 4; ++q) {
        unsigned u = v[q];
        acc[2 * q]     += bf_lo(u);
        acc[2 * q + 1] += bf_hi(u);
    }
}

__global__ __launch_bounds__(256) void gcn_gmm(
    const unsigned short* __restrict__ xb,
    const int* __restrict__ off,
    const unsigned int* __restrict__ csr,
    const unsigned short* __restrict__ wb,
    const float* __restrict__ bias,
    float* __restrict__ out)
{
    __shared__ unsigned short hl[FUSE_NODES][HPAD];   // 17.4 KB

    const int tid  = threadIdx.x;
    const int n0   = blockIdx.x * FUSE_NODES;
    const int lane16 = tid & 15;
    const int col8   = lane16 * 8;

    // ---- Phase A: gather 64 nodes ----
    #pragma unroll
    for (int sweep = 0; sweep < 4; ++sweep) {
        const int nloc = sweep * 16 + (tid >> 4);
        const int n    = n0 + nloc;
        if (n < N_NODES) {
            const int meta  = off[n];
            const int count = meta >> 13;
            const int start = (n >> 10) * BINCAP + (meta & (BINCAP - 1));
            const int end   = start + count;

            float acc[8];
            #pragma unroll
            for (int q = 0; q < 8; ++q) acc[q] = 0.0f;

            int i = start;
            for (; i + 4 <= end; i += 4) {
                int s0 = csr[i], s1 = csr[i + 1], s2 = csr[i + 2], s3 = csr[i + 3];
                u32x4 v0 = *reinterpret_cast<const u32x4*>(xb + (size_t)s0 * DIM + col8);
                u32x4 v1 = *reinterpret_cast<const u32x4*>(xb + (size_t)s1 * DIM + col8);
                u32x4 v2 = *reinterpret_cast<const u32x4*>(xb + (size_t)s2 * DIM + col8);
                u32x4 v3 = *reinterpret_cast<const u32x4*>(xb + (size_t)s3 * DIM + col8);
                acc8(acc, v0); acc8(acc, v1); acc8(acc, v2); acc8(acc, v3);
            }
            for (; i < end; ++i) {
                u32x4 v = *reinterpret_cast<const u32x4*>(xb + (size_t)csr[i] * DIM + col8);
                acc8(acc, v);
            }

            const float inv = 1.0f / fmaxf((float)count, 1.0f);
            const u32x4 xr = *reinterpret_cast<const u32x4*>(xb + (size_t)n * DIM + col8);
            u32x4 o;
            #pragma unroll
            for (int q = 0; q < 4; ++q) {
                float v0 = acc[2 * q]     * inv + bf_lo(xr[q]);
                float v1 = acc[2 * q + 1] * inv + bf_hi(xr[q]);
                o[q] = (unsigned)f2bf(v0) | ((unsigned)f2bf(v1) << 16);
            }
            *reinterpret_cast<u32x4*>(&hl[nloc][col8]) = o;
        }
    }
    __syncthreads();

    // ---- Phase B: MFMA. wave w -> rows [16w, 16w+16) ----
    const int w    = tid >> 6;
    const int lane = tid & 63;
    const int r    = lane & 15;
    const int g    = lane >> 4;
    const int rowbase = n0 + 16 * w;
    if (rowbase >= N_NODES) return;

    bf16x8 af[4];
    #pragma unroll
    for (int t = 0; t < 4; ++t)
        af[t] = *reinterpret_cast<const bf16x8*>(&hl[16 * w + r][32 * t + 8 * g]);

    f32x4 acc[8];
    #pragma unroll
    for (int c = 0; c < 8; ++c) acc[c] = {0.f, 0.f, 0.f, 0.f};

    #pragma unroll
    for (int c = 0; c < 8; ++c) {
        #pragma unroll
        for (int t = 0; t < 4; ++t) {
            bf16x8 wf = *reinterpret_cast<const bf16x8*>(
                wb + (16 * c + r) * DIM + 32 * t + 8 * g);
            acc[c] = __builtin_amdgcn_mfma_f32_16x16x32_bf16(af[t], wf, acc[c], 0, 0, 0);
        }
    }

    #pragma unroll
    for (int c = 0; c < 8; ++c) {
        const float bj = bias[16 * c + r];
        #pragma unroll
        for (int q = 0; q < 4; ++q) {
            const int n = rowbase + 4 * g + q;
            if (n < N_NODES)
                out[(size_t)n * DIM + 16 * c + r] = fmaxf(acc[c][q] + bj, 0.0f);
        }
    }
}

// ---------------------------------------------------------------------------
extern "C" void kernel_launch(void* const* d_in, const int* in_sizes, int n_in,
                              void* d_out, int out_size, void* d_ws, size_t ws_size,
                              hipStream_t stream)
{
    const float* x    = (const float*)d_in[0];
    const int*   eidx = (const int*)d_in[1];
    const float* W    = (const float*)d_in[2];
    const float* bias = (const float*)d_in[3];
    float*       out  = (float*)d_out;

    const int* src = eidx;
    const int* dst = eidx + N_EDGES;

    int* bincur = (int*)d_ws;                               // [128]
    int* off    = bincur + 128;                             // [N]
    unsigned int* bindata = (unsigned int*)(off + 100352);  // [98*8192] -> becomes csr
    unsigned short* wb = (unsigned short*)(bindata + (size_t)N_CHUNKS * BINCAP);
    unsigned short* xb = wb + (size_t)DIM * DIM;            // [N*128] bf16 (in ws now)

    gcn_conv <<<XCONV_XBLOCKS + XCONV_WBLOCKS, 256, 0, stream>>>(
        x, W, (unsigned int*)xb, (unsigned int*)wb, bincur);
    gcn_bin  <<<N_EDGES / EPB, 256, 0, stream>>>(src, dst, bincur, bindata);
    gcn_build<<<N_CHUNKS, 256, 0, stream>>>(bincur, bindata, off);
    gcn_gmm  <<<FUSE_BLOCKS, 256, 0, stream>>>(
        xb, off, bindata, wb, bias, out);
}

// Round 9
// 96.739 us; speedup vs baseline: 1.2304x; 1.2304x over previous
//
#include <hip/hip_runtime.h>
#include <hip/hip_bf16.h>

constexpr int N_NODES = 100000;
constexpr int DIM     = 128;
constexpr int N_EDGES = 640000;

constexpr int CHUNK     = 1024;
constexpr int N_CHUNKS  = (N_NODES + CHUNK - 1) / CHUNK;   // 98
constexpr int BINCAP    = 8192;
constexpr int EPB       = 1024;
constexpr int SRC_BITS  = 17;
constexpr int SRC_MASK  = (1 << SRC_BITS) - 1;

constexpr int XCONV_XBLOCKS = N_NODES * DIM / (256 * 8);   // 6250
constexpr int XCONV_WBLOCKS = DIM * DIM / (256 * 8);       // 8

constexpr int HPAD = DIM + 8;                              // 136 bf16 rows

typedef __attribute__((ext_vector_type(4))) float        f32x4;
typedef __attribute__((ext_vector_type(8))) short        bf16x8;
typedef __attribute__((ext_vector_type(4))) unsigned int u32x4;

static __device__ inline unsigned short f2bf(float f) {
    __hip_bfloat16 h = __float2bfloat16(f);   // RNE
    return *reinterpret_cast<unsigned short*>(&h);
}
static __device__ inline float bf_lo(unsigned u) { return __uint_as_float(u << 16); }
static __device__ inline float bf_hi(unsigned u) { return __uint_as_float(u & 0xffff0000u); }

// ---------------------------------------------------------------------------
// 1) Fused: x->bf16 (-> ws), W->bf16, zero the 98 bin cursors.
// ---------------------------------------------------------------------------
__global__ __launch_bounds__(256) void gcn_conv(const float* __restrict__ x,
                                                const float* __restrict__ W,
                                                unsigned int* __restrict__ xb,
                                                unsigned int* __restrict__ wb,
                                                int* __restrict__ bincur)
{
    const int b   = blockIdx.x;
    const int gid = b * 256 + threadIdx.x;

    if (b == 0 && threadIdx.x < 128) bincur[threadIdx.x] = 0;

    const float*  src;
    unsigned int* dst;
    int i;
    if (b < XCONV_XBLOCKS) {
        src = x;  dst = xb;  i = gid;
    } else {
        src = W;  dst = wb;  i = gid - XCONV_XBLOCKS * 256;
    }
    const f32x4* s4 = reinterpret_cast<const f32x4*>(src);
    f32x4 a = s4[2 * i];
    f32x4 c = s4[2 * i + 1];
    u32x4 o;
    o.x = (unsigned)f2bf(a.x) | ((unsigned)f2bf(a.y) << 16);
    o.y = (unsigned)f2bf(a.z) | ((unsigned)f2bf(a.w) << 16);
    o.z = (unsigned)f2bf(c.x) | ((unsigned)f2bf(c.y) << 16);
    o.w = (unsigned)f2bf(c.z) | ((unsigned)f2bf(c.w) << 16);
    reinterpret_cast<u32x4*>(dst)[i] = o;
}

// ---------------------------------------------------------------------------
// 2) Bin pass: scatter edges into per-chunk regions (packed src|dstlocal).
// ---------------------------------------------------------------------------
__global__ __launch_bounds__(256) void gcn_bin(const int* __restrict__ src,
                                               const int* __restrict__ dst,
                                               int* __restrict__ bincur,
                                               unsigned int* __restrict__ bindata)
{
    __shared__ int bh[N_CHUNKS];
    __shared__ int btb[N_CHUNKS];

    const int t  = threadIdx.x;
    const int e0 = blockIdx.x * EPB + t * 4;

    if (t < N_CHUNKS) bh[t] = 0;
    __syncthreads();

    const int4 s4 = *reinterpret_cast<const int4*>(src + e0);
    const int4 d4 = *reinterpret_cast<const int4*>(dst + e0);

    int bin[4], pos[4];
    unsigned pv[4];
    const int ds[4] = {d4.x, d4.y, d4.z, d4.w};
    const int ss[4] = {s4.x, s4.y, s4.z, s4.w};
    #pragma unroll
    for (int q = 0; q < 4; ++q) {
        bin[q] = ds[q] >> 10;
        pv[q]  = (unsigned)ss[q] | ((unsigned)(ds[q] & (CHUNK - 1)) << SRC_BITS);
        pos[q] = atomicAdd(&bh[bin[q]], 1);
    }
    __syncthreads();

    if (t < N_CHUNKS) btb[t] = atomicAdd(&bincur[t], bh[t]);
    __syncthreads();

    #pragma unroll
    for (int q = 0; q < 4; ++q)
        bindata[(size_t)bin[q] * BINCAP + btb[bin[q]] + pos[q]] = pv[q];
}

// ---------------------------------------------------------------------------
// 3) Build pass: per-chunk LDS counting sort -> dense csr + off metadata.
// ---------------------------------------------------------------------------
__global__ __launch_bounds__(256) void gcn_build(const int* __restrict__ bincur,
                                                 unsigned int* __restrict__ bindata,
                                                 int* __restrict__ off)
{
    __shared__ unsigned stage[BINCAP];
    __shared__ int hist[CHUNK];
    __shared__ int s[256];

    const int c  = blockIdx.x;
    const int t  = threadIdx.x;
    const int nb = min(bincur[c], BINCAP);
    unsigned int* region = bindata + (size_t)c * BINCAP;

    for (int e = t; e < nb; e += 256) stage[e] = region[e];
    #pragma unroll
    for (int q = 0; q < 4; ++q) hist[t + 256 * q] = 0;
    __syncthreads();

    for (int e = t; e < nb; e += 256)
        atomicAdd(&hist[stage[e] >> SRC_BITS], 1);
    __syncthreads();

    int h0 = hist[4 * t + 0], h1 = hist[4 * t + 1];
    int h2 = hist[4 * t + 2], h3 = hist[4 * t + 3];
    s[t] = h0 + h1 + h2 + h3;
    __syncthreads();
    for (int d = 1; d < 256; d <<= 1) {
        int add = (t >= d) ? s[t - d] : 0;
        __syncthreads();
        s[t] += add;
        __syncthreads();
    }
    int excl = (t > 0) ? s[t - 1] : 0;

    const int st0 = excl;
    const int st1 = excl + h0;
    const int st2 = excl + h0 + h1;
    const int st3 = excl + h0 + h1 + h2;
    hist[4 * t + 0] = st0;  hist[4 * t + 1] = st1;
    hist[4 * t + 2] = st2;  hist[4 * t + 3] = st3;

    const int nbase = c * CHUNK;
    if (nbase + 4 * t + 0 < N_NODES) off[nbase + 4 * t + 0] = st0 | (h0 << 13);
    if (nbase + 4 * t + 1 < N_NODES) off[nbase + 4 * t + 1] = st1 | (h1 << 13);
    if (nbase + 4 * t + 2 < N_NODES) off[nbase + 4 * t + 2] = st2 | (h2 << 13);
    if (nbase + 4 * t + 3 < N_NODES) off[nbase + 4 * t + 3] = st3 | (h3 << 13);
    __syncthreads();

    for (int e = t; e < nb; e += 256) {
        unsigned v  = stage[e];
        int slot    = atomicAdd(&hist[v >> SRC_BITS], 1);
        region[slot] = v & SRC_MASK;
    }
}

// ---------------------------------------------------------------------------
// 4) FUSED gather + MFMA, 16 nodes/block (R7 gather geometry preserved).
//    Phase A: thread (nloc, lane16) gathers one 8-dim slice -> LDS [16][136].
//    Phase B: wave w computes c-columns {2w, 2w+1} (8 MFMAs), bias+relu, store.
// ---------------------------------------------------------------------------
static __device__ inline void acc8(float* acc, u32x4 v) {
    #pragma unroll
    for (int q = 0; q < 4; ++q) {
        unsigned u = v[q];
        acc[2 * q]     += bf_lo(u);
        acc[2 * q + 1] += bf_hi(u);
    }
}

__global__ __launch_bounds__(256) void gcn_gmm(
    const unsigned short* __restrict__ xb,
    const int* __restrict__ off,
    const unsigned int* __restrict__ csr,
    const unsigned short* __restrict__ wb,
    const float* __restrict__ bias,
    float* __restrict__ out)
{
    __shared__ unsigned short hl[16][HPAD];   // 4.4 KB

    const int tid    = threadIdx.x;
    const int n0     = blockIdx.x * 16;       // grid exact: 6250 blocks
    const int nloc   = tid >> 4;
    const int lane16 = tid & 15;
    const int col8   = lane16 * 8;
    const int n      = n0 + nloc;

    // ---- Phase A: gather one node-slice per thread ----
    {
        const int meta  = off[n];
        const int count = meta >> 13;
        const int start = (n >> 10) * BINCAP + (meta & (BINCAP - 1));
        const int end   = start + count;

        float acc[8];
        #pragma unroll
        for (int q = 0; q < 8; ++q) acc[q] = 0.0f;

        int i = start;
        for (; i + 4 <= end; i += 4) {
            int s0 = csr[i], s1 = csr[i + 1], s2 = csr[i + 2], s3 = csr[i + 3];
            u32x4 v0 = *reinterpret_cast<const u32x4*>(xb + (size_t)s0 * DIM + col8);
            u32x4 v1 = *reinterpret_cast<const u32x4*>(xb + (size_t)s1 * DIM + col8);
            u32x4 v2 = *reinterpret_cast<const u32x4*>(xb + (size_t)s2 * DIM + col8);
            u32x4 v3 = *reinterpret_cast<const u32x4*>(xb + (size_t)s3 * DIM + col8);
            acc8(acc, v0); acc8(acc, v1); acc8(acc, v2); acc8(acc, v3);
        }
        for (; i < end; ++i) {
            u32x4 v = *reinterpret_cast<const u32x4*>(xb + (size_t)csr[i] * DIM + col8);
            acc8(acc, v);
        }

        const float inv = 1.0f / fmaxf((float)count, 1.0f);
        const u32x4 xr = *reinterpret_cast<const u32x4*>(xb + (size_t)n * DIM + col8);
        u32x4 o;
        #pragma unroll
        for (int q = 0; q < 4; ++q) {
            float v0 = acc[2 * q]     * inv + bf_lo(xr[q]);
            float v1 = acc[2 * q + 1] * inv + bf_hi(xr[q]);
            o[q] = (unsigned)f2bf(v0) | ((unsigned)f2bf(v1) << 16);
        }
        *reinterpret_cast<u32x4*>(&hl[nloc][col8]) = o;
    }
    __syncthreads();

    // ---- Phase B: wave w -> output columns c in {2w, 2w+1} ----
    const int w    = tid >> 6;
    const int lane = tid & 63;
    const int r    = lane & 15;
    const int g    = lane >> 4;

    bf16x8 af[4];
    #pragma unroll
    for (int t = 0; t < 4; ++t)
        af[t] = *reinterpret_cast<const bf16x8*>(&hl[r][32 * t + 8 * g]);

    #pragma unroll
    for (int cc = 0; cc < 2; ++cc) {
        const int c = 2 * w + cc;
        f32x4 acc = {0.f, 0.f, 0.f, 0.f};
        #pragma unroll
        for (int t = 0; t < 4; ++t) {
            bf16x8 wf = *reinterpret_cast<const bf16x8*>(
                wb + (16 * c + r) * DIM + 32 * t + 8 * g);
            acc = __builtin_amdgcn_mfma_f32_16x16x32_bf16(af[t], wf, acc, 0, 0, 0);
        }
        const float bj = bias[16 * c + r];
        #pragma unroll
        for (int q = 0; q < 4; ++q)
            out[(size_t)(n0 + 4 * g + q) * DIM + 16 * c + r] =
                fmaxf(acc[q] + bj, 0.0f);
    }
}

// ---------------------------------------------------------------------------
extern "C" void kernel_launch(void* const* d_in, const int* in_sizes, int n_in,
                              void* d_out, int out_size, void* d_ws, size_t ws_size,
                              hipStream_t stream)
{
    const float* x    = (const float*)d_in[0];
    const int*   eidx = (const int*)d_in[1];
    const float* W    = (const float*)d_in[2];
    const float* bias = (const float*)d_in[3];
    float*       out  = (float*)d_out;

    const int* src = eidx;
    const int* dst = eidx + N_EDGES;

    int* bincur = (int*)d_ws;                               // [128]
    int* off    = bincur + 128;                             // [N]
    unsigned int* bindata = (unsigned int*)(off + 100352);  // [98*8192] -> becomes csr
    unsigned short* wb = (unsigned short*)(bindata + (size_t)N_CHUNKS * BINCAP);
    unsigned short* xb = wb + (size_t)DIM * DIM;            // [N*128] bf16

    gcn_conv <<<XCONV_XBLOCKS + XCONV_WBLOCKS, 256, 0, stream>>>(
        x, W, (unsigned int*)xb, (unsigned int*)wb, bincur);
    gcn_bin  <<<N_EDGES / EPB, 256, 0, stream>>>(src, dst, bincur, bindata);
    gcn_build<<<N_CHUNKS, 256, 0, stream>>>(bincur, bindata, off);
    gcn_gmm  <<<N_NODES / 16, 256, 0, stream>>>(
        xb, off, bindata, wb, bias, out);
}